// Round 6
// baseline (12.251 us; speedup 1.0000x reference)
//
#include <hip/hip_runtime.h>

// BoundaryLoss collapses analytically:
//   boundary = min(edt(~mask), edt(mask)) == 0 at EVERY pixel
//   (each pixel is a feature pixel of one of the two sets, where its EDT is 0),
//   so weights == 1.0 exactly and the op is mean(BCE(inputs, targets)).
//
// R6: R5 retry — __builtin_nontemporal_load needs a NATIVE vector type
// (ext_vector_type(4)), not HIP_vector_type. Same plan: cluster all
// 64B/thread of loads before any math; nt loads (read-once streaming).

typedef float f32x4 __attribute__((ext_vector_type(4)));

static constexpr int N_TOTAL = 32 * 320 * 320;   // 3,276,800
static constexpr int N4      = N_TOTAL / 4;      // 819,200 float4 elements
static constexpr int THREADS = 256;
static constexpr int BLOCKS  = 1600;             // 1600*256*2 == N4 exactly
static constexpr int STRIDE  = BLOCKS * THREADS;

__device__ __forceinline__ float bce4(f32x4 xv, f32x4 tv) {
    float acc = 0.0f;
    #pragma unroll
    for (int j = 0; j < 4; ++j) {
        float e = __expf(-xv[j]);                       // v_exp_f32
        float p = __builtin_amdgcn_rcpf(1.0f + e);      // v_rcp_f32 (sigmoid)
        acc += -tv[j]          * __logf(p + 1e-6f)
               - (1.0f - tv[j]) * __logf(1.0f - p + 1e-6f);
    }
    return acc;
}

__global__ __launch_bounds__(THREADS) void bce_partial_kernel(
    const f32x4* __restrict__ x4, const f32x4* __restrict__ t4,
    float* __restrict__ partial) {
    const int tid = blockIdx.x * THREADS + threadIdx.x;

    // Cluster all 4 independent 16B loads (nt: read-once, bypass L2 fill)
    f32x4 xv0 = __builtin_nontemporal_load(&x4[tid]);
    f32x4 tv0 = __builtin_nontemporal_load(&t4[tid]);
    f32x4 xv1 = __builtin_nontemporal_load(&x4[tid + STRIDE]);
    f32x4 tv1 = __builtin_nontemporal_load(&t4[tid + STRIDE]);

    float acc = bce4(xv0, tv0) + bce4(xv1, tv1);

    // wave (64-lane) shuffle reduction
    #pragma unroll
    for (int off = 32; off > 0; off >>= 1)
        acc += __shfl_down(acc, off, 64);
    __shared__ float sdata[THREADS / 64];
    const int lane = threadIdx.x & 63;
    const int wave = threadIdx.x >> 6;
    if (lane == 0) sdata[wave] = acc;
    __syncthreads();
    if (threadIdx.x == 0) {
        float s = 0.0f;
        #pragma unroll
        for (int w = 0; w < THREADS / 64; ++w) s += sdata[w];
        partial[blockIdx.x] = s;
    }
}

static constexpr int THREADS2 = 1024;

__global__ __launch_bounds__(THREADS2) void final_reduce_kernel(
    const float* __restrict__ partial, float* __restrict__ out) {
    float acc = 0.0f;
    for (int i = threadIdx.x; i < BLOCKS; i += THREADS2) acc += partial[i];
    #pragma unroll
    for (int off = 32; off > 0; off >>= 1)
        acc += __shfl_down(acc, off, 64);
    __shared__ float sdata[THREADS2 / 64];
    const int lane = threadIdx.x & 63;
    const int wave = threadIdx.x >> 6;
    if (lane == 0) sdata[wave] = acc;
    __syncthreads();
    if (threadIdx.x == 0) {
        float s = 0.0f;
        #pragma unroll
        for (int w = 0; w < THREADS2 / 64; ++w) s += sdata[w];
        out[0] = s / (float)N_TOTAL;
    }
}

extern "C" void kernel_launch(void* const* d_in, const int* in_sizes, int n_in,
                              void* d_out, int out_size, void* d_ws, size_t ws_size,
                              hipStream_t stream) {
    const f32x4* x4 = (const f32x4*)d_in[0];     // inputs  [32,1,320,320] f32
    const f32x4* t4 = (const f32x4*)d_in[1];     // targets [32,1,320,320] f32
    float* partial  = (float*)d_ws;              // BLOCKS floats of scratch
    float* out      = (float*)d_out;             // scalar f32

    bce_partial_kernel<<<BLOCKS, THREADS, 0, stream>>>(x4, t4, partial);
    final_reduce_kernel<<<1, THREADS2, 0, stream>>>(partial, out);
}

// Round 7
// 12.167 us; speedup vs baseline: 1.0070x; 1.0070x over previous
//
#include <hip/hip_runtime.h>

// BoundaryLoss collapses analytically:
//   boundary = min(edt(~mask), edt(mask)) == 0 at EVERY pixel
//   (each pixel is a feature pixel of one of the two sets, where its EDT is 0),
//   so weights == 1.0 exactly and the op is mean(BCE(inputs, targets)).
//
// R7: exact revert to R4 (best measured: 11.85 us). R6's nt-load/clustering
// variant regressed (+0.4 us); R3's single-kernel fusion regressed (+15 us).
// Structure: k1 = 1600 blocks x 256 thr x 2 float4 (~25 waves/CU, latency-
// hiding-limited not math-limited), k2 = 1-block final reduce (dispatch floor).

static constexpr int N_TOTAL = 32 * 320 * 320;   // 3,276,800
static constexpr int N4      = N_TOTAL / 4;      // 819,200 float4 elements
static constexpr int THREADS = 256;
static constexpr int BLOCKS  = 1600;             // 1600*256*2 == N4 exactly
static constexpr int ITERS   = 2;

__global__ __launch_bounds__(THREADS) void bce_partial_kernel(
    const float4* __restrict__ x4, const float4* __restrict__ t4,
    float* __restrict__ partial) {
    const int tid    = blockIdx.x * THREADS + threadIdx.x;
    const int stride = BLOCKS * THREADS;

    float acc = 0.0f;
    #pragma unroll
    for (int it = 0; it < ITERS; ++it) {
        const int i = tid + it * stride;
        float4 xv = x4[i];
        float4 tv = t4[i];
        float xs[4] = {xv.x, xv.y, xv.z, xv.w};
        float ts[4] = {tv.x, tv.y, tv.z, tv.w};
        #pragma unroll
        for (int j = 0; j < 4; ++j) {
            float e = __expf(-xs[j]);                       // v_exp_f32
            float p = __builtin_amdgcn_rcpf(1.0f + e);      // v_rcp_f32 (sigmoid)
            acc += -ts[j]          * __logf(p + 1e-6f)
                   - (1.0f - ts[j]) * __logf(1.0f - p + 1e-6f);
        }
    }

    // wave (64-lane) shuffle reduction
    #pragma unroll
    for (int off = 32; off > 0; off >>= 1)
        acc += __shfl_down(acc, off, 64);
    __shared__ float sdata[THREADS / 64];
    const int lane = threadIdx.x & 63;
    const int wave = threadIdx.x >> 6;
    if (lane == 0) sdata[wave] = acc;
    __syncthreads();
    if (threadIdx.x == 0) {
        float s = 0.0f;
        #pragma unroll
        for (int w = 0; w < THREADS / 64; ++w) s += sdata[w];
        partial[blockIdx.x] = s;
    }
}

static constexpr int THREADS2 = 1024;

__global__ __launch_bounds__(THREADS2) void final_reduce_kernel(
    const float* __restrict__ partial, float* __restrict__ out) {
    float acc = 0.0f;
    for (int i = threadIdx.x; i < BLOCKS; i += THREADS2) acc += partial[i];
    #pragma unroll
    for (int off = 32; off > 0; off >>= 1)
        acc += __shfl_down(acc, off, 64);
    __shared__ float sdata[THREADS2 / 64];
    const int lane = threadIdx.x & 63;
    const int wave = threadIdx.x >> 6;
    if (lane == 0) sdata[wave] = acc;
    __syncthreads();
    if (threadIdx.x == 0) {
        float s = 0.0f;
        #pragma unroll
        for (int w = 0; w < THREADS2 / 64; ++w) s += sdata[w];
        out[0] = s / (float)N_TOTAL;
    }
}

extern "C" void kernel_launch(void* const* d_in, const int* in_sizes, int n_in,
                              void* d_out, int out_size, void* d_ws, size_t ws_size,
                              hipStream_t stream) {
    const float4* x4 = (const float4*)d_in[0];   // inputs  [32,1,320,320] f32
    const float4* t4 = (const float4*)d_in[1];   // targets [32,1,320,320] f32
    float* partial   = (float*)d_ws;             // BLOCKS floats of scratch
    float* out       = (float*)d_out;            // scalar f32

    bce_partial_kernel<<<BLOCKS, THREADS, 0, stream>>>(x4, t4, partial);
    final_reduce_kernel<<<1, THREADS2, 0, stream>>>(partial, out);
}